// Round 1
// baseline (917.529 us; speedup 1.0000x reference)
//
#include <hip/hip_runtime.h>
#include <math.h>

#define LL 8
#define G 17
#define NH 30
#define D 768
#define N 4096
#define CH 31              // NH+1
#define CELLS (G*G*G)      // 4913
#define CSTRIDE (CH*D)     // 23808 floats per cell
#define NBIN 16            // bins per axis (floor(p) in [0,15])

__device__ __forceinline__ int iclip(int i){ return i<0?0:(i>G-1?G-1:i); }

// ---------------- K1: per-sample weights/indices, dist, bin histogram ----------------
__global__ void k_prep(const float* __restrict__ samples, const float* __restrict__ last_point,
                       float* __restrict__ wxyz, int* __restrict__ ixyz,
                       float* __restrict__ dist, int* __restrict__ sampleBin,
                       int* __restrict__ binCount){
    int s = blockIdx.x*blockDim.x + threadIdx.x;
    if (s >= N) return;
    float x0 = samples[s*3+0], y0 = samples[s*3+1], z0 = samples[s*3+2];
    float p[3] = {x0 + (float)LL, y0 + (float)LL, z0 + (float)LL};
    float fv[3], cv[3], dv[3]; int fi[3], ci[3];
    for (int a=0;a<3;a++){
        fv[a]=floorf(p[a]); cv[a]=ceilf(p[a]); dv[a]=p[a]-fv[a];
        fi[a]=(int)fv[a]; ci[a]=(int)cv[a];
    }
    // x axis: slots [fx-1, fx, fx+1, fx+2]
    {
        int fx=fi[0]; float dx=dv[0];
        float mlo=(fx>0)?1.f:0.f, mhi=(fx+2<G)?1.f:0.f;
        float cnt=2.f+mlo+mhi;
        float w[4]={(1.f-dx)*mlo/cnt,(2.f-dx)/cnt,(1.f+dx)/cnt,dx*mhi/cnt};
        int id[4]={iclip(fx-1),iclip(fx),iclip(fx+1),iclip(fx+2)};
        for(int i=0;i<4;i++){ wxyz[s*12+i]=w[i]; ixyz[s*12+i]=id[i]; }
    }
    // y axis: slots [fy-1, fy, cy, cy+1]
    {
        int fy=fi[1], cy=ci[1]; float dy=dv[1];
        float mlo=(fy>0)?1.f:0.f, mhi=(fy+2<G)?1.f:0.f;
        float cnt=2.f+mlo+mhi;
        float w[4]={(1.f-dy)*mlo/cnt,(2.f-dy)/cnt,(1.f+dy)/cnt,dy*mhi/cnt};
        int id[4]={iclip(fy-1),iclip(fy),iclip(cy),iclip(cy+1)};
        for(int i=0;i<4;i++){ wxyz[s*12+4+i]=w[i]; ixyz[s*12+4+i]=id[i]; }
    }
    // z axis: slots [fz-1, fz, cz, cz+1]
    {
        int fz=fi[2], cz=ci[2]; float dz=dv[2];
        float mlo=(fz>0)?1.f:0.f, mhi=(fz+2<G)?1.f:0.f;
        float cnt=2.f+mlo+mhi;
        float w[4]={(1.f-dz)*mlo/cnt,(2.f-dz)/cnt,(1.f+dz)/cnt,dz*mhi/cnt};
        int id[4]={iclip(fz-1),iclip(fz),iclip(cz),iclip(cz+1)};
        for(int i=0;i<4;i++){ wxyz[s*12+8+i]=w[i]; ixyz[s*12+8+i]=id[i]; }
    }
    // dist to next sample (last uses last_point)
    float nx,ny,nz;
    if (s < N-1){ nx=samples[(s+1)*3+0]; ny=samples[(s+1)*3+1]; nz=samples[(s+1)*3+2]; }
    else        { nx=last_point[0];      ny=last_point[1];      nz=last_point[2]; }
    float ddx=x0-nx, ddy=y0-ny, ddz=z0-nz;
    dist[s]=sqrtf(ddx*ddx+ddy*ddy+ddz*ddz);
    // bin by base cell
    int bx=min(max(fi[0],0),NBIN-1), by=min(max(fi[1],0),NBIN-1), bz=min(max(fi[2],0),NBIN-1);
    int bin=(bz*NBIN+by)*NBIN+bx;
    sampleBin[s]=bin;
    atomicAdd(&binCount[bin],1);
}

// ---------------- K1b: exclusive scan over 4096 bin counts (single block) ----------------
__global__ void k_binscan(const int* __restrict__ binCount, int* __restrict__ binStart,
                          int* __restrict__ binCursor){
    __shared__ int sh[256];
    __shared__ int srun;
    int t = threadIdx.x;
    if (t==0) srun=0;
    __syncthreads();
    for (int base=0; base<NBIN*NBIN*NBIN; base+=256){
        int v = binCount[base+t];
        sh[t]=v; __syncthreads();
        for (int off=1; off<256; off<<=1){
            int u = (t>=off)? sh[t-off] : 0;
            __syncthreads();
            sh[t]+=u;
            __syncthreads();
        }
        int incl = sh[t];
        int st = srun + incl - v;
        binStart[base+t]=st; binCursor[base+t]=st;
        __syncthreads();
        if (t==255) srun += incl;
        __syncthreads();
    }
}

// ---------------- K1c: scatter sample ids into bin order ----------------
__global__ void k_scatter(const int* __restrict__ sampleBin, int* __restrict__ binCursor,
                          int* __restrict__ binned){
    int s = blockIdx.x*blockDim.x + threadIdx.x;
    if (s>=N) return;
    int b=sampleBin[s];
    int pos=atomicAdd(&binCursor[b],1);
    binned[pos]=s;
}

// ---------------- K2: density[n,d] = sum_cells W * E[c,30,d] ----------------
__global__ __launch_bounds__(256) void k_density(const float* __restrict__ emb,
                       const float* __restrict__ wxyz, const int* __restrict__ ixyz,
                       float* __restrict__ density){
    int s = blockIdx.x; int t = threadIdx.x;
    __shared__ float w[12]; __shared__ int idx[12];
    if (t<12){ w[t]=wxyz[s*12+t]; idx[t]=ixyz[s*12+t]; }
    __syncthreads();
    float a0=0.f,a1=0.f,a2=0.f;
    for (int i=0;i<4;i++){
        float wx=w[i]; if (wx==0.f) continue; int X=idx[i];
        for (int j=0;j<4;j++){
            float wxy=wx*w[4+j]; if (wxy==0.f) continue; int Y=idx[4+j];
            for (int k=0;k<4;k++){
                float www=wxy*w[8+k]; if (www==0.f) continue; int Z=idx[8+k];
                const float* p = emb + (size_t)((X*G+Y)*G+Z)*CSTRIDE + NH*D;
                a0 += www*p[t]; a1 += www*p[256+t]; a2 += www*p[512+t];
            }
        }
    }
    float* dr = density + (size_t)s*D;
    dr[t]=a0; dr[256+t]=a1; dr[512+t]=a2;
}

// ---------------- transpose RxC -> CxR (64x64 LDS tiles, block (64,4)) ----------------
__global__ void k_transpose(const float* __restrict__ in, float* __restrict__ out,
                            int R, int C){
    __shared__ float tile[64][65];
    int tx=threadIdx.x, ty=threadIdx.y;
    int c0=blockIdx.x*64, r0=blockIdx.y*64;
    #pragma unroll
    for (int k=0;k<16;k++){
        int r=r0+ty+k*4;
        tile[ty+k*4][tx] = in[(size_t)r*C + c0 + tx];
    }
    __syncthreads();
    #pragma unroll
    for (int k=0;k<16;k++){
        int c=c0+ty+k*4;
        out[(size_t)c*R + r0 + tx] = tile[tx][ty+k*4];
    }
}

// ---------------- K3: per-column serial scan (1 wave / column) ----------------
__global__ void k_scan(const float* __restrict__ density_t, const float* __restrict__ dist,
                       float* __restrict__ wgt_t){
    int wave = threadIdx.x>>6, lane = threadIdx.x&63;
    int d = blockIdx.x*4 + wave;
    const float* col = density_t + (size_t)d*N;
    float* out = wgt_t + (size_t)d*N;
    float carry=0.f;
    for (int c0=0;c0<N;c0+=64){
        int n=c0+lane;
        float v=col[n];
        float sd=fmaxf(v,0.f)*dist[n];
        float x=sd;
        #pragma unroll
        for (int off=1; off<64; off<<=1){
            float u=__shfl_up(x,(unsigned)off,64);
            if (lane>=off) x+=u;
        }
        float incl=x+carry;
        // wgt = exp(-(incl-sd)) - exp(-incl)
        out[n]=expf(sd-incl)-expf(-incl);
        carry=__shfl(incl,63,64);
    }
}

// ---------------- K4: A[c,d] = sum_n W[n,c]*wgt[n,d]  (gather per cell) ----------------
__global__ __launch_bounds__(256) void k_accumA(const float* __restrict__ wgt,
                       const float* __restrict__ wxyz, const int* __restrict__ ixyz,
                       const int* __restrict__ binStart, const int* __restrict__ binCount,
                       const int* __restrict__ binned, float* __restrict__ A){
    int c=blockIdx.x, t=threadIdx.x;
    int x=c/(G*G); int rem=c-x*G*G; int y=rem/G; int z=rem-y*G;
    float a0=0.f,a1=0.f,a2=0.f;
    int bx0=max(0,x-2), bx1=min(NBIN-1,x+1);
    int by0=max(0,y-2), by1=min(NBIN-1,y+1);
    int bz0=max(0,z-2), bz1=min(NBIN-1,z+1);
    for (int bz=bz0;bz<=bz1;bz++)
    for (int by=by0;by<=by1;by++)
    for (int bx=bx0;bx<=bx1;bx++){
        int bin=(bz*NBIN+by)*NBIN+bx;
        int st=binStart[bin], cnt=binCount[bin];
        for (int q=0;q<cnt;q++){
            int s=binned[st+q];
            const float* w=wxyz+(size_t)s*12;
            const int* id=ixyz+(size_t)s*12;
            float px=0.f,py=0.f,pz=0.f;
            #pragma unroll
            for (int i=0;i<4;i++){
                px += (id[i]  ==x)? w[i]  :0.f;
                py += (id[4+i]==y)? w[4+i]:0.f;
                pz += (id[8+i]==z)? w[8+i]:0.f;
            }
            float wt=px*py*pz;
            if (wt!=0.f){
                const float* wr=wgt+(size_t)s*D;
                a0+=wt*wr[t]; a1+=wt*wr[256+t]; a2+=wt*wr[512+t];
            }
        }
    }
    float* Ar=A+(size_t)c*D;
    Ar[t]=a0; Ar[256+t]=a1; Ar[512+t]=a2;
}

// ---------------- K5: out[h,d] = sum_c A[c,d]*E[c,h,d] ----------------
#define CPG 16
__global__ __launch_bounds__(256) void k_out(const float* __restrict__ emb,
                      const float* __restrict__ A, float* __restrict__ out){
    int t=threadIdx.x;
    int d=blockIdx.y*256+t;
    int c0=blockIdx.x*CPG;
    int c1=min(CELLS,c0+CPG);
    float acc[NH];
    #pragma unroll
    for (int h=0;h<NH;h++) acc[h]=0.f;
    for (int c=c0;c<c1;c++){
        float a=A[(size_t)c*D+d];
        const float* e=emb+(size_t)c*CSTRIDE+d;
        #pragma unroll
        for (int h=0;h<NH;h++) acc[h]+=a*e[h*D];
    }
    #pragma unroll
    for (int h=0;h<NH;h++) atomicAdd(&out[h*D+d],acc[h]);
}

extern "C" void kernel_launch(void* const* d_in, const int* in_sizes, int n_in,
                              void* d_out, int out_size, void* d_ws, size_t ws_size,
                              hipStream_t stream){
    const float* samples   = (const float*)d_in[0];
    const float* last_point= (const float*)d_in[1];
    const float* emb       = (const float*)d_in[2];
    char* ws=(char*)d_ws;
    // ws layout (bytes)
    float* wxyz     =(float*)(ws + 0);        // 4096*12*4 = 196608
    int*   ixyz     =(int*)  (ws + 196608);   // 196608
    float* dist     =(float*)(ws + 393216);   // 16384
    int*   sampleBin=(int*)  (ws + 409600);   // 16384
    int*   binCount =(int*)  (ws + 425984);   // 16384
    int*   binStart =(int*)  (ws + 442368);   // 16384
    int*   binCursor=(int*)  (ws + 458752);   // 16384
    int*   binned   =(int*)  (ws + 475136);   // 16384
    float* density  =(float*)(ws + 524288);               // 12.58 MB
    float* density_t=(float*)(ws + 524288 + 12582912);    // 12.58 MB
    float* wgt_t    =(float*)(ws + 524288 + 2*12582912);  // 12.58 MB
    float* wgt      = density;                            // alias: density dead after T1
    float* A        =(float*)(ws + 524288 + 3*12582912);  // 15.09 MB

    hipMemsetAsync(binCount, 0, 4096*sizeof(int), stream);
    hipMemsetAsync(d_out, 0, (size_t)out_size*sizeof(float), stream);

    k_prep   <<<N/256, 256, 0, stream>>>(samples, last_point, wxyz, ixyz, dist, sampleBin, binCount);
    k_binscan<<<1, 256, 0, stream>>>(binCount, binStart, binCursor);
    k_scatter<<<N/256, 256, 0, stream>>>(sampleBin, binCursor, binned);
    k_density<<<N, 256, 0, stream>>>(emb, wxyz, ixyz, density);
    dim3 tb(64,4);
    k_transpose<<<dim3(D/64, N/64), tb, 0, stream>>>(density, density_t, N, D);
    k_scan   <<<D/4, 256, 0, stream>>>(density_t, dist, wgt_t);
    k_transpose<<<dim3(N/64, D/64), tb, 0, stream>>>(wgt_t, wgt, D, N);
    k_accumA <<<CELLS, 256, 0, stream>>>(wgt, wxyz, ixyz, binStart, binCount, binned, A);
    k_out    <<<dim3((CELLS+CPG-1)/CPG, D/256), 256, 0, stream>>>(emb, A, (float*)d_out);
}

// Round 2
// 851.331 us; speedup vs baseline: 1.0778x; 1.0778x over previous
//
#include <hip/hip_runtime.h>
#include <math.h>

#define LL 8
#define G 17
#define NH 30
#define D 768
#define N 4096
#define CH 31              // NH+1
#define CELLS (G*G*G)      // 4913
#define CSTRIDE (CH*D)     // 23808 floats per cell
#define NBIN 16            // bins per axis (floor(p) in [0,15])

__device__ __forceinline__ int iclip(int i){ return i<0?0:(i>G-1?G-1:i); }

// ---------------- K1: per-sample weights/indices, dist, bin histogram ----------------
__global__ void k_prep(const float* __restrict__ samples, const float* __restrict__ last_point,
                       float* __restrict__ wxyz, int* __restrict__ ixyz,
                       float* __restrict__ dist, int* __restrict__ sampleBin,
                       int* __restrict__ binCount){
    int s = blockIdx.x*blockDim.x + threadIdx.x;
    if (s >= N) return;
    float x0 = samples[s*3+0], y0 = samples[s*3+1], z0 = samples[s*3+2];
    float p[3] = {x0 + (float)LL, y0 + (float)LL, z0 + (float)LL};
    float fv[3], cv[3], dv[3]; int fi[3], ci[3];
    for (int a=0;a<3;a++){
        fv[a]=floorf(p[a]); cv[a]=ceilf(p[a]); dv[a]=p[a]-fv[a];
        fi[a]=(int)fv[a]; ci[a]=(int)cv[a];
    }
    {
        int fx=fi[0]; float dx=dv[0];
        float mlo=(fx>0)?1.f:0.f, mhi=(fx+2<G)?1.f:0.f;
        float cnt=2.f+mlo+mhi;
        float w[4]={(1.f-dx)*mlo/cnt,(2.f-dx)/cnt,(1.f+dx)/cnt,dx*mhi/cnt};
        int id[4]={iclip(fx-1),iclip(fx),iclip(fx+1),iclip(fx+2)};
        for(int i=0;i<4;i++){ wxyz[s*12+i]=w[i]; ixyz[s*12+i]=id[i]; }
    }
    {
        int fy=fi[1], cy=ci[1]; float dy=dv[1];
        float mlo=(fy>0)?1.f:0.f, mhi=(fy+2<G)?1.f:0.f;
        float cnt=2.f+mlo+mhi;
        float w[4]={(1.f-dy)*mlo/cnt,(2.f-dy)/cnt,(1.f+dy)/cnt,dy*mhi/cnt};
        int id[4]={iclip(fy-1),iclip(fy),iclip(cy),iclip(cy+1)};
        for(int i=0;i<4;i++){ wxyz[s*12+4+i]=w[i]; ixyz[s*12+4+i]=id[i]; }
    }
    {
        int fz=fi[2], cz=ci[2]; float dz=dv[2];
        float mlo=(fz>0)?1.f:0.f, mhi=(fz+2<G)?1.f:0.f;
        float cnt=2.f+mlo+mhi;
        float w[4]={(1.f-dz)*mlo/cnt,(2.f-dz)/cnt,(1.f+dz)/cnt,dz*mhi/cnt};
        int id[4]={iclip(fz-1),iclip(fz),iclip(cz),iclip(cz+1)};
        for(int i=0;i<4;i++){ wxyz[s*12+8+i]=w[i]; ixyz[s*12+8+i]=id[i]; }
    }
    float nx,ny,nz;
    if (s < N-1){ nx=samples[(s+1)*3+0]; ny=samples[(s+1)*3+1]; nz=samples[(s+1)*3+2]; }
    else        { nx=last_point[0];      ny=last_point[1];      nz=last_point[2]; }
    float ddx=x0-nx, ddy=y0-ny, ddz=z0-nz;
    dist[s]=sqrtf(ddx*ddx+ddy*ddy+ddz*ddz);
    int bx=min(max(fi[0],0),NBIN-1), by=min(max(fi[1],0),NBIN-1), bz=min(max(fi[2],0),NBIN-1);
    int bin=(bz*NBIN+by)*NBIN+bx;
    sampleBin[s]=bin;
    atomicAdd(&binCount[bin],1);
}

// ---------------- K1b: exclusive scan over 4096 bin counts (single block) ----------------
__global__ void k_binscan(const int* __restrict__ binCount, int* __restrict__ binStart,
                          int* __restrict__ binCursor){
    __shared__ int sh[256];
    __shared__ int srun;
    int t = threadIdx.x;
    if (t==0) srun=0;
    __syncthreads();
    for (int base=0; base<NBIN*NBIN*NBIN; base+=256){
        int v = binCount[base+t];
        sh[t]=v; __syncthreads();
        for (int off=1; off<256; off<<=1){
            int u = (t>=off)? sh[t-off] : 0;
            __syncthreads();
            sh[t]+=u;
            __syncthreads();
        }
        int incl = sh[t];
        int st = srun + incl - v;
        binStart[base+t]=st; binCursor[base+t]=st;
        __syncthreads();
        if (t==255) srun += incl;
        __syncthreads();
    }
}

// ---------------- K1c: scatter sample ids into bin order ----------------
__global__ void k_scatter(const int* __restrict__ sampleBin, int* __restrict__ binCursor,
                          int* __restrict__ binned){
    int s = blockIdx.x*blockDim.x + threadIdx.x;
    if (s>=N) return;
    int b=sampleBin[s];
    int pos=atomicAdd(&binCursor[b],1);
    binned[pos]=s;
}

// ---------------- K2: density[n,d] = sum_cells W * E[c,30,d] ----------------
// XCD-swizzled: blocks with blockIdx%8==k (round-robin -> XCD k) process the
// spatially-contiguous chunk binned[k*512..(k+1)*512) -> cell footprint fits 4MB L2.
__global__ __launch_bounds__(192) void k_density(const float* __restrict__ emb,
                       const float* __restrict__ wxyz, const int* __restrict__ ixyz,
                       const int* __restrict__ binned,
                       float* __restrict__ density){
    int b = blockIdx.x;
    int s = binned[((b & 7) << 9) | (b >> 3)];   // N/8 = 512 per XCD chunk
    int t = threadIdx.x;
    __shared__ float w[12]; __shared__ int idx[12];
    if (t<12){ w[t]=wxyz[s*12+t]; idx[t]=ixyz[s*12+t]; }
    __syncthreads();
    float4 acc = make_float4(0.f,0.f,0.f,0.f);
    for (int i=0;i<4;i++){
        float wx=w[i]; if (wx==0.f) continue; int X=idx[i];
        for (int j=0;j<4;j++){
            float wxy=wx*w[4+j]; if (wxy==0.f) continue; int Y=idx[4+j];
            for (int k=0;k<4;k++){
                float www=wxy*w[8+k]; if (www==0.f) continue; int Z=idx[8+k];
                const float4* p = (const float4*)(emb + (size_t)((X*G+Y)*G+Z)*CSTRIDE + NH*D);
                float4 v = p[t];
                acc.x += www*v.x; acc.y += www*v.y; acc.z += www*v.z; acc.w += www*v.w;
            }
        }
    }
    ((float4*)(density + (size_t)s*D))[t] = acc;
}

// ---------------- transpose RxC -> CxR (64x64 LDS tiles, block (64,4)) ----------------
__global__ void k_transpose(const float* __restrict__ in, float* __restrict__ out,
                            int R, int C){
    __shared__ float tile[64][65];
    int tx=threadIdx.x, ty=threadIdx.y;
    int c0=blockIdx.x*64, r0=blockIdx.y*64;
    #pragma unroll
    for (int k=0;k<16;k++){
        int r=r0+ty+k*4;
        tile[ty+k*4][tx] = in[(size_t)r*C + c0 + tx];
    }
    __syncthreads();
    #pragma unroll
    for (int k=0;k<16;k++){
        int c=c0+ty+k*4;
        out[(size_t)c*R + r0 + tx] = tile[tx][ty+k*4];
    }
}

// ---------------- K3: per-column serial scan (1 wave / column) ----------------
__global__ void k_scan(const float* __restrict__ density_t, const float* __restrict__ dist,
                       float* __restrict__ wgt_t){
    int wave = threadIdx.x>>6, lane = threadIdx.x&63;
    int d = blockIdx.x*4 + wave;
    const float* col = density_t + (size_t)d*N;
    float* out = wgt_t + (size_t)d*N;
    float carry=0.f;
    for (int c0=0;c0<N;c0+=64){
        int n=c0+lane;
        float v=col[n];
        float sd=fmaxf(v,0.f)*dist[n];
        float x=sd;
        #pragma unroll
        for (int off=1; off<64; off<<=1){
            float u=__shfl_up(x,(unsigned)off,64);
            if (lane>=off) x+=u;
        }
        float incl=x+carry;
        out[n]=expf(sd-incl)-expf(-incl);
        carry=__shfl(incl,63,64);
    }
}

// ---------------- K4: A[c,d] = sum_n W[n,c]*wgt[n,d]  (gather per cell) ----------------
// XCD-swizzled: XCD k gets the contiguous cell range [k*615, ...) whose sample
// wgt-row footprint (~3MB) fits its L2.
__global__ __launch_bounds__(192) void k_accumA(const float* __restrict__ wgt,
                       const float* __restrict__ wxyz, const int* __restrict__ ixyz,
                       const int* __restrict__ binStart, const int* __restrict__ binCount,
                       const int* __restrict__ binned, float* __restrict__ A){
    int b = blockIdx.x;
    int c = (b & 7) * 615 + (b >> 3);   // ceil(4913/8)=615; grid.x = 8*615 = 4920
    if (c >= CELLS) return;
    int t = threadIdx.x;
    int x=c/(G*G); int rem=c-x*G*G; int y=rem/G; int z=rem-y*G;
    float4 acc = make_float4(0.f,0.f,0.f,0.f);
    int bx0=max(0,x-2), bx1=min(NBIN-1,x+1);
    int by0=max(0,y-2), by1=min(NBIN-1,y+1);
    int bz0=max(0,z-2), bz1=min(NBIN-1,z+1);
    for (int bz=bz0;bz<=bz1;bz++)
    for (int by=by0;by<=by1;by++)
    for (int bx=bx0;bx<=bx1;bx++){
        int bin=(bz*NBIN+by)*NBIN+bx;
        int st=binStart[bin], cnt=binCount[bin];
        for (int q=0;q<cnt;q++){
            int s=binned[st+q];
            const float* w=wxyz+(size_t)s*12;
            const int* id=ixyz+(size_t)s*12;
            float px=0.f,py=0.f,pz=0.f;
            #pragma unroll
            for (int i=0;i<4;i++){
                px += (id[i]  ==x)? w[i]  :0.f;
                py += (id[4+i]==y)? w[4+i]:0.f;
                pz += (id[8+i]==z)? w[8+i]:0.f;
            }
            float wt=px*py*pz;
            if (wt!=0.f){
                const float4* wr=(const float4*)(wgt+(size_t)s*D);
                float4 v=wr[t];
                acc.x+=wt*v.x; acc.y+=wt*v.y; acc.z+=wt*v.z; acc.w+=wt*v.w;
            }
        }
    }
    ((float4*)(A+(size_t)c*D))[t]=acc;
}

// ---------------- K5: out[h,d] = sum_c A[c,d]*E[c,h,d] ----------------
#define CPG 32
__global__ __launch_bounds__(256) void k_out(const float* __restrict__ emb,
                      const float* __restrict__ A, float* __restrict__ out){
    int t=threadIdx.x;
    int d=blockIdx.y*256+t;
    int c0=blockIdx.x*CPG;
    int c1=min(CELLS,c0+CPG);
    float acc[NH];
    #pragma unroll
    for (int h=0;h<NH;h++) acc[h]=0.f;
    for (int c=c0;c<c1;c++){
        float a=A[(size_t)c*D+d];
        const float* e=emb+(size_t)c*CSTRIDE+d;
        #pragma unroll
        for (int h=0;h<NH;h++) acc[h]+=a*e[h*D];
    }
    #pragma unroll
    for (int h=0;h<NH;h++) atomicAdd(&out[h*D+d],acc[h]);
}

extern "C" void kernel_launch(void* const* d_in, const int* in_sizes, int n_in,
                              void* d_out, int out_size, void* d_ws, size_t ws_size,
                              hipStream_t stream){
    const float* samples   = (const float*)d_in[0];
    const float* last_point= (const float*)d_in[1];
    const float* emb       = (const float*)d_in[2];
    char* ws=(char*)d_ws;
    float* wxyz     =(float*)(ws + 0);        // 196608 B
    int*   ixyz     =(int*)  (ws + 196608);   // 196608 B
    float* dist     =(float*)(ws + 393216);   // 16384 B
    int*   sampleBin=(int*)  (ws + 409600);
    int*   binCount =(int*)  (ws + 425984);
    int*   binStart =(int*)  (ws + 442368);
    int*   binCursor=(int*)  (ws + 458752);
    int*   binned   =(int*)  (ws + 475136);
    float* density  =(float*)(ws + 524288);               // 12.58 MB
    float* density_t=(float*)(ws + 524288 + 12582912);    // 12.58 MB
    float* wgt_t    =(float*)(ws + 524288 + 2*12582912);  // 12.58 MB
    float* wgt      = density;                            // alias: density dead after T1
    float* A        =(float*)(ws + 524288 + 3*12582912);  // 15.09 MB

    hipMemsetAsync(binCount, 0, 4096*sizeof(int), stream);
    hipMemsetAsync(d_out, 0, (size_t)out_size*sizeof(float), stream);

    k_prep   <<<N/256, 256, 0, stream>>>(samples, last_point, wxyz, ixyz, dist, sampleBin, binCount);
    k_binscan<<<1, 256, 0, stream>>>(binCount, binStart, binCursor);
    k_scatter<<<N/256, 256, 0, stream>>>(sampleBin, binCursor, binned);
    k_density<<<N, 192, 0, stream>>>(emb, wxyz, ixyz, binned, density);
    dim3 tb(64,4);
    k_transpose<<<dim3(D/64, N/64), tb, 0, stream>>>(density, density_t, N, D);
    k_scan   <<<D/4, 256, 0, stream>>>(density_t, dist, wgt_t);
    k_transpose<<<dim3(N/64, D/64), tb, 0, stream>>>(wgt_t, wgt, D, N);
    k_accumA <<<8*615, 192, 0, stream>>>(wgt, wxyz, ixyz, binStart, binCount, binned, A);
    k_out    <<<dim3((CELLS+CPG-1)/CPG, D/256), 256, 0, stream>>>(emb, A, (float*)d_out);
}

// Round 3
// 750.852 us; speedup vs baseline: 1.2220x; 1.1338x over previous
//
#include <hip/hip_runtime.h>
#include <math.h>

#define LL 8
#define G 17
#define NH 30
#define D 768
#define N 4096
#define CH 31              // NH+1
#define CELLS (G*G*G)      // 4913
#define CSTRIDE (CH*D)     // 23808 floats per cell
#define NBIN 16            // bins per axis (floor(p) in [0,15])
#define CPG 32
#define NCHUNK ((CELLS+CPG-1)/CPG)   // 154

__device__ __forceinline__ int iclip(int i){ return i<0?0:(i>G-1?G-1:i); }

// ---------------- K1: per-sample weights/indices, dist, bin histogram ----------------
__global__ void k_prep(const float* __restrict__ samples, const float* __restrict__ last_point,
                       float* __restrict__ wxyz, int* __restrict__ ixyz,
                       float* __restrict__ dist, int* __restrict__ sampleBin,
                       int* __restrict__ binCount){
    int s = blockIdx.x*blockDim.x + threadIdx.x;
    if (s >= N) return;
    float x0 = samples[s*3+0], y0 = samples[s*3+1], z0 = samples[s*3+2];
    float p[3] = {x0 + (float)LL, y0 + (float)LL, z0 + (float)LL};
    float fv[3], cv[3], dv[3]; int fi[3], ci[3];
    for (int a=0;a<3;a++){
        fv[a]=floorf(p[a]); cv[a]=ceilf(p[a]); dv[a]=p[a]-fv[a];
        fi[a]=(int)fv[a]; ci[a]=(int)cv[a];
    }
    {
        int fx=fi[0]; float dx=dv[0];
        float mlo=(fx>0)?1.f:0.f, mhi=(fx+2<G)?1.f:0.f;
        float cnt=2.f+mlo+mhi;
        float w[4]={(1.f-dx)*mlo/cnt,(2.f-dx)/cnt,(1.f+dx)/cnt,dx*mhi/cnt};
        int id[4]={iclip(fx-1),iclip(fx),iclip(fx+1),iclip(fx+2)};
        for(int i=0;i<4;i++){ wxyz[s*12+i]=w[i]; ixyz[s*12+i]=id[i]; }
    }
    {
        int fy=fi[1], cy=ci[1]; float dy=dv[1];
        float mlo=(fy>0)?1.f:0.f, mhi=(fy+2<G)?1.f:0.f;
        float cnt=2.f+mlo+mhi;
        float w[4]={(1.f-dy)*mlo/cnt,(2.f-dy)/cnt,(1.f+dy)/cnt,dy*mhi/cnt};
        int id[4]={iclip(fy-1),iclip(fy),iclip(cy),iclip(cy+1)};
        for(int i=0;i<4;i++){ wxyz[s*12+4+i]=w[i]; ixyz[s*12+4+i]=id[i]; }
    }
    {
        int fz=fi[2], cz=ci[2]; float dz=dv[2];
        float mlo=(fz>0)?1.f:0.f, mhi=(fz+2<G)?1.f:0.f;
        float cnt=2.f+mlo+mhi;
        float w[4]={(1.f-dz)*mlo/cnt,(2.f-dz)/cnt,(1.f+dz)/cnt,dz*mhi/cnt};
        int id[4]={iclip(fz-1),iclip(fz),iclip(cz),iclip(cz+1)};
        for(int i=0;i<4;i++){ wxyz[s*12+8+i]=w[i]; ixyz[s*12+8+i]=id[i]; }
    }
    float nx,ny,nz;
    if (s < N-1){ nx=samples[(s+1)*3+0]; ny=samples[(s+1)*3+1]; nz=samples[(s+1)*3+2]; }
    else        { nx=last_point[0];      ny=last_point[1];      nz=last_point[2]; }
    float ddx=x0-nx, ddy=y0-ny, ddz=z0-nz;
    dist[s]=sqrtf(ddx*ddx+ddy*ddy+ddz*ddz);
    int bx=min(max(fi[0],0),NBIN-1), by=min(max(fi[1],0),NBIN-1), bz=min(max(fi[2],0),NBIN-1);
    int bin=(bz*NBIN+by)*NBIN+bx;
    sampleBin[s]=bin;
    atomicAdd(&binCount[bin],1);
}

// ---------------- K1b: exclusive scan over 4096 bin counts (single block) ----------------
__global__ void k_binscan(const int* __restrict__ binCount, int* __restrict__ binStart,
                          int* __restrict__ binCursor){
    __shared__ int sh[256];
    __shared__ int srun;
    int t = threadIdx.x;
    if (t==0) srun=0;
    __syncthreads();
    for (int base=0; base<NBIN*NBIN*NBIN; base+=256){
        int v = binCount[base+t];
        sh[t]=v; __syncthreads();
        for (int off=1; off<256; off<<=1){
            int u = (t>=off)? sh[t-off] : 0;
            __syncthreads();
            sh[t]+=u;
            __syncthreads();
        }
        int incl = sh[t];
        int st = srun + incl - v;
        binStart[base+t]=st; binCursor[base+t]=st;
        __syncthreads();
        if (t==255) srun += incl;
        __syncthreads();
    }
}

// ---------------- K1c: scatter sample ids into bin order ----------------
__global__ void k_scatter(const int* __restrict__ sampleBin, int* __restrict__ binCursor,
                          int* __restrict__ binned){
    int s = blockIdx.x*blockDim.x + threadIdx.x;
    if (s>=N) return;
    int b=sampleBin[s];
    int pos=atomicAdd(&binCursor[b],1);
    binned[pos]=s;
}

// ---------------- K2: density[n,d] = sum_cells W * E[c,30,d] ----------------
__global__ __launch_bounds__(192) void k_density(const float* __restrict__ emb,
                       const float* __restrict__ wxyz, const int* __restrict__ ixyz,
                       const int* __restrict__ binned,
                       float* __restrict__ density){
    int b = blockIdx.x;
    int s = binned[((b & 7) << 9) | (b >> 3)];   // N/8 = 512 per XCD chunk
    int t = threadIdx.x;
    __shared__ float w[12]; __shared__ int idx[12];
    if (t<12){ w[t]=wxyz[s*12+t]; idx[t]=ixyz[s*12+t]; }
    __syncthreads();
    float4 acc = make_float4(0.f,0.f,0.f,0.f);
    for (int i=0;i<4;i++){
        float wx=w[i]; if (wx==0.f) continue; int X=idx[i];
        for (int j=0;j<4;j++){
            float wxy=wx*w[4+j]; if (wxy==0.f) continue; int Y=idx[4+j];
            for (int k=0;k<4;k++){
                float www=wxy*w[8+k]; if (www==0.f) continue; int Z=idx[8+k];
                const float4* p = (const float4*)(emb + (size_t)((X*G+Y)*G+Z)*CSTRIDE + NH*D);
                float4 v = p[t];
                acc.x += www*v.x; acc.y += www*v.y; acc.z += www*v.z; acc.w += www*v.w;
            }
        }
    }
    ((float4*)(density + (size_t)s*D))[t] = acc;
}

// ---------------- transpose RxC -> CxR (64x64 LDS tiles, block (64,4)) ----------------
__global__ void k_transpose(const float* __restrict__ in, float* __restrict__ out,
                            int R, int C){
    __shared__ float tile[64][65];
    int tx=threadIdx.x, ty=threadIdx.y;
    int c0=blockIdx.x*64, r0=blockIdx.y*64;
    #pragma unroll
    for (int k=0;k<16;k++){
        int r=r0+ty+k*4;
        tile[ty+k*4][tx] = in[(size_t)r*C + c0 + tx];
    }
    __syncthreads();
    #pragma unroll
    for (int k=0;k<16;k++){
        int c=c0+ty+k*4;
        out[(size_t)c*R + r0 + tx] = tile[tx][ty+k*4];
    }
}

// ---------------- K3: full-column scan, one block per column ----------------
// buf is padded: SIDX(n) = n + n/16 breaks the 16-stride bank pattern
#define SIDX(n) ((n) + ((n)>>4))
__global__ __launch_bounds__(256) void k_scan(const float* __restrict__ density_t,
                       const float* __restrict__ dist, float* __restrict__ wgt_t){
    __shared__ float buf[4096 + 256];
    __shared__ float wtot[4];
    int t = threadIdx.x;
    int d = blockIdx.x;
    const float* col = density_t + (size_t)d*N;
    float* out = wgt_t + (size_t)d*N;
    #pragma unroll
    for (int i=0;i<16;i++){
        int n = i*256 + t;
        buf[SIDX(n)] = fmaxf(col[n], 0.f) * dist[n];
    }
    __syncthreads();
    int lane = t & 63, wave = t >> 6;
    float vals[16]; float sum = 0.f;
    #pragma unroll
    for (int j=0;j<16;j++){ vals[j] = buf[SIDX(t*16+j)]; sum += vals[j]; }
    float x = sum;
    #pragma unroll
    for (int off=1; off<64; off<<=1){
        float u = __shfl_up(x, (unsigned)off, 64);
        if (lane >= off) x += u;
    }
    if (lane == 63) wtot[wave] = x;
    float thread_excl = x - sum;
    __syncthreads();
    float wexcl = 0.f;
    for (int w2=0; w2<4; w2++) if (w2 < wave) wexcl += wtot[w2];
    float run = wexcl + thread_excl;
    #pragma unroll
    for (int j=0;j<16;j++){
        float sd = vals[j];
        run += sd;                                   // inclusive cumsum
        buf[SIDX(t*16+j)] = expf(sd-run) - expf(-run); // T*alpha
    }
    __syncthreads();
    #pragma unroll
    for (int i=0;i<16;i++){
        int n = i*256 + t;
        out[n] = buf[SIDX(n)];
    }
}

// ---------------- K4: A[c,d] = sum_n W[n,c]*wgt[n,d] (LDS work-list per cell) ----------------
#define MAXS 1024
__global__ __launch_bounds__(192) void k_accumA(const float* __restrict__ wgt,
                       const float* __restrict__ wxyz, const int* __restrict__ ixyz,
                       const int* __restrict__ binStart, const int* __restrict__ binCount,
                       const int* __restrict__ binned, float* __restrict__ A){
    int b = blockIdx.x;
    int c = (b & 7) * 615 + (b >> 3);   // XCD-contiguous cell ranges
    if (c >= CELLS) return;
    int t = threadIdx.x;
    int x=c/(G*G); int rem=c-x*G*G; int y=rem/G; int z=rem-y*G;
    __shared__ int   ls[MAXS];
    __shared__ float lw[MAXS];
    __shared__ int   lcount;
    if (t==0) lcount = 0;
    __syncthreads();
    int bx0=max(0,x-2), bx1=min(NBIN-1,x+1);
    int by0=max(0,y-2), by1=min(NBIN-1,y+1);
    int bz0=max(0,z-2), bz1=min(NBIN-1,z+1);
    int nx=bx1-bx0+1, ny=by1-by0+1, nz=bz1-bz0+1;
    int nb = nx*ny*nz;
    for (int bi=t; bi<nb; bi+=192){
        int bxo = bi % nx; int r2 = bi / nx;
        int byo = r2 % ny; int bzo = r2 / ny;
        int bin = ((bz0+bzo)*NBIN + (by0+byo))*NBIN + (bx0+bxo);
        int st = binStart[bin], cnt = binCount[bin];
        for (int q=0;q<cnt;q++){
            int s = binned[st+q];
            const float* w = wxyz + (size_t)s*12;
            const int* id  = ixyz + (size_t)s*12;
            float px=0.f,py=0.f,pz=0.f;
            #pragma unroll
            for (int i=0;i<4;i++){
                px += (id[i]  ==x)? w[i]  :0.f;
                py += (id[4+i]==y)? w[4+i]:0.f;
                pz += (id[8+i]==z)? w[8+i]:0.f;
            }
            float wt = px*py*pz;
            if (wt != 0.f){
                int pos = atomicAdd(&lcount, 1);
                if (pos < MAXS){ ls[pos]=s; lw[pos]=wt; }
            }
        }
    }
    __syncthreads();
    int m = min(lcount, MAXS);
    float4 acc = make_float4(0.f,0.f,0.f,0.f);
    for (int i=0;i<m;i++){
        int s = ls[i]; float wt = lw[i];
        float4 v = ((const float4*)(wgt + (size_t)s*D))[t];
        acc.x += wt*v.x; acc.y += wt*v.y; acc.z += wt*v.z; acc.w += wt*v.w;
    }
    ((float4*)(A + (size_t)c*D))[t] = acc;
}

// ---------------- K5a: partial[chunk,h,d] = sum_{c in chunk} A[c,d]*E[c,h,d] ----------------
__global__ __launch_bounds__(256) void k_out(const float* __restrict__ emb,
                      const float* __restrict__ A, float* __restrict__ partial){
    int t=threadIdx.x;
    int d=blockIdx.y*256+t;
    int chunk=blockIdx.x;
    int c0=chunk*CPG;
    int c1=min(CELLS,c0+CPG);
    float acc[NH];
    #pragma unroll
    for (int h=0;h<NH;h++) acc[h]=0.f;
    for (int c=c0;c<c1;c++){
        float a=A[(size_t)c*D+d];
        const float* e=emb+(size_t)c*CSTRIDE+d;
        #pragma unroll
        for (int h=0;h<NH;h++) acc[h]+=a*e[h*D];
    }
    float* pr = partial + (size_t)chunk*NH*D + d;
    #pragma unroll
    for (int h=0;h<NH;h++) pr[h*D] = acc[h];
}

// ---------------- K5b: out[i] = sum_chunk partial[chunk,i] ----------------
__global__ __launch_bounds__(256) void k_reduce(const float* __restrict__ partial,
                       float* __restrict__ out){
    int i = blockIdx.x*256 + threadIdx.x;
    if (i >= NH*D) return;
    float s = 0.f;
    for (int c=0;c<NCHUNK;c++) s += partial[(size_t)c*NH*D + i];
    out[i] = s;
}

extern "C" void kernel_launch(void* const* d_in, const int* in_sizes, int n_in,
                              void* d_out, int out_size, void* d_ws, size_t ws_size,
                              hipStream_t stream){
    const float* samples   = (const float*)d_in[0];
    const float* last_point= (const float*)d_in[1];
    const float* emb       = (const float*)d_in[2];
    char* ws=(char*)d_ws;
    float* wxyz     =(float*)(ws + 0);
    int*   ixyz     =(int*)  (ws + 196608);
    float* dist     =(float*)(ws + 393216);
    int*   sampleBin=(int*)  (ws + 409600);
    int*   binCount =(int*)  (ws + 425984);
    int*   binStart =(int*)  (ws + 442368);
    int*   binCursor=(int*)  (ws + 458752);
    int*   binned   =(int*)  (ws + 475136);
    float* density  =(float*)(ws + 524288);               // 12.58 MB
    float* density_t=(float*)(ws + 524288 + 12582912);    // 12.58 MB
    float* wgt_t    =(float*)(ws + 524288 + 2*12582912);  // 12.58 MB
    float* wgt      = density;                            // alias: density dead after T1
    float* A        =(float*)(ws + 524288 + 3*12582912);  // 15.09 MB
    float* partial  =(float*)(ws + 524288 + 3*12582912 + 15093504); // 14.2 MB

    hipMemsetAsync(binCount, 0, 4096*sizeof(int), stream);

    k_prep   <<<N/256, 256, 0, stream>>>(samples, last_point, wxyz, ixyz, dist, sampleBin, binCount);
    k_binscan<<<1, 256, 0, stream>>>(binCount, binStart, binCursor);
    k_scatter<<<N/256, 256, 0, stream>>>(sampleBin, binCursor, binned);
    k_density<<<N, 192, 0, stream>>>(emb, wxyz, ixyz, binned, density);
    dim3 tb(64,4);
    k_transpose<<<dim3(D/64, N/64), tb, 0, stream>>>(density, density_t, N, D);
    k_scan   <<<D, 256, 0, stream>>>(density_t, dist, wgt_t);
    k_transpose<<<dim3(N/64, D/64), tb, 0, stream>>>(wgt_t, wgt, D, N);
    k_accumA <<<8*615, 192, 0, stream>>>(wgt, wxyz, ixyz, binStart, binCount, binned, A);
    k_out    <<<dim3(NCHUNK, D/256), 256, 0, stream>>>(emb, A, partial);
    k_reduce <<<(NH*D+255)/256, 256, 0, stream>>>(partial, (float*)d_out);
}